// Round 15
// baseline (81.234 us; speedup 1.0000x reference)
//
#include <hip/hip_runtime.h>

#define NB 4
#define NC 16
#define NP 76800
#define NK 100
#define NITER 10
#define BW2 0.0256f
#define TPB 256
#define PT 4
#define TILEP (TPB*PT)        // 1024 points per accum block
#define NTILES (NP/TILEP)     // 75
#define KS 4                  // k-split
#define KPB (NK/KS)           // 25
// label: 2 points/thread, strided by TPB (both coalesced)
#define LPT 2
#define LTILEP (TPB*LPT)      // 512
#define LNT (NP/LTILEP)       // 150

// ws float-offsets
#define MEANS_OFF 0                            // [2][NB*NK][NC]
#define M2G_OFF   (MEANS_OFF + 2*NB*NK*NC)     // [NB*NK] m2 of current global means
#define GNUM_OFF  (M2G_OFF + NB*NK)            // [3][NB*NK][NC]
#define GDEN_OFF  (GNUM_OFF + 3*NB*NK*NC)      // [3][NB*NK]
#define ACNT_OFF  (GDEN_OFF + 3*NB*NK)         // int[NB*KS] active counts
#define FIN_OFF   (ACNT_OFF + NB*KS)           // int[2]: finalR, finalM

__device__ __forceinline__ const float* uni(const float* p, int off) {
    return p + __builtin_amdgcn_readfirstlane(off);
}

__global__ void ms_init(const float* __restrict__ feat, const int* __restrict__ seed,
                        float* __restrict__ ws) {
    int t = blockIdx.x * blockDim.x + threadIdx.x;
    int stride = gridDim.x * blockDim.x;
    int* wsi = (int*)ws;
    for (int i = t; i < 3 * NB * NK * NC + 3 * NB * NK; i += stride)
        ws[GNUM_OFF + i] = 0.f;
    if (t < NB * KS) wsi[ACNT_OFF + t] = KPB;
    if (t < 2) wsi[FIN_OFF + t] = 0;
    if (t < NB * NK) {
        int b = t / NK;
        int idx = seed[t];
        float nm[NC];
        #pragma unroll
        for (int c = 0; c < NC; ++c) nm[c] = feat[((size_t)b * NC + c) * NP + idx];
        float s = 0.f;
        #pragma unroll
        for (int c = 0; c < NC; ++c) s += nm[c] * nm[c];
        float* m = ws + MEANS_OFF + NB * NK * NC + t * NC;  // buffer 1 = means_{-1}
        #pragma unroll
        for (int c = 0; c < NC; ++c) m[c] = nm[c];
        ws[M2G_OFF + t] = s;
    }
}

// Per-k bitwise convergence skip (exact). Global-convergence early-exit.
// it==0: identity update; means read from global via wave-uniform scalar loads,
// with a 1-deep register prefetch (kept from R14; neutral but harmless).
__global__ __launch_bounds__(TPB, 4) void ms_accum(const float* __restrict__ feat,
                                                   float* __restrict__ ws,
                                                   int rIdx, int aIdx, int zIdx,
                                                   int prevM, int curM, int it) {
    __shared__ float sm[KPB][NC];
    __shared__ float sm2k[KPB];
    __shared__ float snum[KPB][NC];
    __shared__ float sden[KPB];
    __shared__ unsigned char sflag[KPB];
    __shared__ short act[KPB];
    __shared__ int nact;
    int* wsi = (int*)ws;

    if (it >= 1) {  // global-convergence early exit (uniform scalar reads)
        int total = 0;
        #pragma unroll
        for (int i = 0; i < NB * KS; ++i) total += wsi[ACNT_OFF + i];
        if (total == 0) return;
    }

    const int bid = blockIdx.x;
    const int ks = bid & (KS - 1);
    const int t2 = bid >> 2;
    const int b = t2 / NTILES;
    const int tile = t2 % NTILES;
    const int tid = threadIdx.x;
    const int kbeg = ks * KPB;

    float* gnumR = ws + GNUM_OFF + (size_t)rIdx * NB * NK * NC + (size_t)b * NK * NC;
    float* gnumA = ws + GNUM_OFF + (size_t)aIdx * NB * NK * NC + (size_t)b * NK * NC;
    float* gnumZ = ws + GNUM_OFF + (size_t)zIdx * NB * NK * NC + (size_t)b * NK * NC;
    float* gdenR = ws + GDEN_OFF + rIdx * NB * NK + b * NK;
    float* gdenA = ws + GDEN_OFF + aIdx * NB * NK + b * NK;
    float* gdenZ = ws + GDEN_OFF + zIdx * NB * NK + b * NK;
    float* mPrev = ws + MEANS_OFF + (size_t)prevM * NB * NK * NC + (size_t)b * NK * NC;
    float* mCur  = ws + MEANS_OFF + (size_t)curM  * NB * NK * NC + (size_t)b * NK * NC;

    const bool isPersist = (ks == 0 && tile == 0);

    for (int i = tid; i < KPB * NC; i += TPB) (&snum[0][0])[i] = 0.f;
    if (tid < KPB) sden[tid] = 0.f;

    if (it == 0) {
        if (isPersist && tid < NK) {
            const float4* mp4 = reinterpret_cast<const float4*>(mPrev + tid * NC);
            float4* mc4 = reinterpret_cast<float4*>(mCur + tid * NC);
            mc4[0] = mp4[0]; mc4[1] = mp4[1]; mc4[2] = mp4[2]; mc4[3] = mp4[3];
            if (tid == 0) { wsi[FIN_OFF] = aIdx; wsi[FIN_OFF + 1] = curM; }
        }
        if (ks == 1 && tile == 0) {
            for (int i = tid; i < NK * NC; i += TPB) gnumZ[i] = 0.f;
            if (tid < NK) gdenZ[tid] = 0.f;
        }
        __syncthreads();

        const int p0 = tile * TILEP + tid * PT;
        float fA[NC], fB[NC], fC[NC], fD[NC];
        #pragma unroll
        for (int c = 0; c < NC; ++c) {
            float4 v = *reinterpret_cast<const float4*>(feat + ((size_t)b * NC + c) * NP + p0);
            fA[c] = v.x; fB[c] = v.y; fC[c] = v.z; fD[c] = v.w;
        }
        float f2A = 0.f, f2B = 0.f, f2C = 0.f, f2D = 0.f;
        #pragma unroll
        for (int c = 0; c < NC; ++c) f2A += fA[c] * fA[c];
        #pragma unroll
        for (int c = 0; c < NC; ++c) f2B += fB[c] * fB[c];
        #pragma unroll
        for (int c = 0; c < NC; ++c) f2C += fC[c] * fC[c];
        #pragma unroll
        for (int c = 0; c < NC; ++c) f2D += fD[c] * fD[c];

        const float* m2g = ws + M2G_OFF + b * NK;
        float cm[NC], cm2;
        {
            const float* mr = uni(mPrev, kbeg * NC);
            #pragma unroll
            for (int c = 0; c < NC; ++c) cm[c] = mr[c];
            cm2 = *uni(m2g, kbeg);
        }
        for (int k = kbeg; k < kbeg + KPB; ++k) {
            const int kn = (k + 1 < kbeg + KPB) ? (k + 1) : kbeg;
            const float* mrn = uni(mPrev, kn * NC);
            float nm_[NC];
            #pragma unroll
            for (int c = 0; c < NC; ++c) nm_[c] = mrn[c];
            float nm2 = *uni(m2g, kn);

            float dA = 0.f, dB = 0.f, dC = 0.f, dD = 0.f;
            #pragma unroll
            for (int c = 0; c < NC; ++c) {
                float mc = cm[c];
                dA = fmaf(fA[c], mc, dA);
                dB = fmaf(fB[c], mc, dB);
                dC = fmaf(fC[c], mc, dC);
                dD = fmaf(fD[c], mc, dD);
            }
            float d2A = (f2A - 2.f * dA) + cm2;
            float d2B = (f2B - 2.f * dB) + cm2;
            float d2C = (f2C - 2.f * dC) + cm2;
            float d2D = (f2D - 2.f * dD) + cm2;
            bool hA = d2A < BW2, hB = d2B < BW2, hC = d2C < BW2, hD = d2D < BW2;
            if (__any(hA | hB | hC | hD)) {  // rare
                int loc = k - kbeg;
                if (hA) {
                    #pragma unroll
                    for (int c = 0; c < NC; ++c) atomicAdd(&snum[loc][c], fA[c]);
                    atomicAdd(&sden[loc], 1.f);
                }
                if (hB) {
                    #pragma unroll
                    for (int c = 0; c < NC; ++c) atomicAdd(&snum[loc][c], fB[c]);
                    atomicAdd(&sden[loc], 1.f);
                }
                if (hC) {
                    #pragma unroll
                    for (int c = 0; c < NC; ++c) atomicAdd(&snum[loc][c], fC[c]);
                    atomicAdd(&sden[loc], 1.f);
                }
                if (hD) {
                    #pragma unroll
                    for (int c = 0; c < NC; ++c) atomicAdd(&snum[loc][c], fD[c]);
                    atomicAdd(&sden[loc], 1.f);
                }
            }
            #pragma unroll
            for (int c = 0; c < NC; ++c) cm[c] = nm_[c];
            cm2 = nm2;
        }

        __syncthreads();
        for (int i = tid; i < KPB * NC; i += TPB) {
            float v = (&snum[0][0])[i];
            if (v != 0.f) atomicAdd(&gnumA[kbeg * NC + i], v);
        }
        if (tid < KPB) {
            float v = sden[tid];
            if (v != 0.f) atomicAdd(&gdenA[kbeg + tid], v);
        }
        return;
    }

    // ---- it >= 1: trimmed prologue + flags + persist/copy + acnt publish ----
    const int nloc = isPersist ? NK : KPB;
    if (tid < nloc) {
        const int k = isPersist ? tid : (kbeg + tid);
        float den = gdenR[k];
        const float4* gn4 = reinterpret_cast<const float4*>(gnumR + k * NC);
        const float4* mp4 = reinterpret_cast<const float4*>(mPrev + k * NC);
        float4 g0 = gn4[0], g1 = gn4[1], g2 = gn4[2], g3 = gn4[3];
        float4 o0 = mp4[0], o1 = mp4[1], o2 = mp4[2], o3 = mp4[3];
        float gg[NC] = {g0.x,g0.y,g0.z,g0.w, g1.x,g1.y,g1.z,g1.w,
                        g2.x,g2.y,g2.z,g2.w, g3.x,g3.y,g3.z,g3.w};
        float oo[NC] = {o0.x,o0.y,o0.z,o0.w, o1.x,o1.y,o1.z,o1.w,
                        o2.x,o2.y,o2.z,o2.w, o3.x,o3.y,o3.z,o3.w};
        float inv = fmaxf(den, 1.f);
        bool pos = den > 0.f;
        float nm[NC];
        #pragma unroll
        for (int c = 0; c < NC; ++c) nm[c] = pos ? (gg[c] / inv) : oo[c];
        bool same = true;
        #pragma unroll
        for (int c = 0; c < NC; ++c)
            same = same && (__float_as_uint(nm[c]) == __float_as_uint(oo[c]));
        float s = 0.f;
        #pragma unroll
        for (int c = 0; c < NC; ++c) s += nm[c] * nm[c];
        const int loc = k - kbeg;
        if (loc >= 0 && loc < KPB) {
            #pragma unroll
            for (int c = 0; c < NC; ++c) sm[loc][c] = nm[c];
            sm2k[loc] = s;
            sflag[loc] = same ? (unsigned char)1 : (unsigned char)0;
        }
        if (isPersist) {
            float4* mc4 = reinterpret_cast<float4*>(mCur + k * NC);
            mc4[0] = make_float4(nm[0], nm[1], nm[2], nm[3]);
            mc4[1] = make_float4(nm[4], nm[5], nm[6], nm[7]);
            mc4[2] = make_float4(nm[8], nm[9], nm[10], nm[11]);
            mc4[3] = make_float4(nm[12], nm[13], nm[14], nm[15]);
            ws[M2G_OFF + b * NK + k] = s;
            if (same) {  // converged k: sums bitwise equal -> copy
                float4* ga4 = reinterpret_cast<float4*>(gnumA + k * NC);
                ga4[0] = g0; ga4[1] = g1; ga4[2] = g2; ga4[3] = g3;
                gdenA[k] = den;
            }
            if (tid == 0) { wsi[FIN_OFF] = aIdx; wsi[FIN_OFF + 1] = curM; }
        }
    }
    if (ks == 1 && tile == 0) {
        for (int i = tid; i < NK * NC; i += TPB) gnumZ[i] = 0.f;
        if (tid < NK) gdenZ[tid] = 0.f;
    }
    __syncthreads();

    if (tid == 0) {
        int n = 0;
        for (int loc = 0; loc < KPB; ++loc)
            if (!sflag[loc]) act[n++] = (short)loc;
        nact = n;
        if (tile == 0) wsi[ACNT_OFF + b * KS + ks] = n;
    }
    __syncthreads();
    if (nact == 0) return;

    const int p0 = tile * TILEP + tid * PT;
    float fA[NC], fB[NC], fC[NC], fD[NC];
    #pragma unroll
    for (int c = 0; c < NC; ++c) {
        float4 v = *reinterpret_cast<const float4*>(feat + ((size_t)b * NC + c) * NP + p0);
        fA[c] = v.x; fB[c] = v.y; fC[c] = v.z; fD[c] = v.w;
    }
    float f2A = 0.f, f2B = 0.f, f2C = 0.f, f2D = 0.f;
    #pragma unroll
    for (int c = 0; c < NC; ++c) f2A += fA[c] * fA[c];
    #pragma unroll
    for (int c = 0; c < NC; ++c) f2B += fB[c] * fB[c];
    #pragma unroll
    for (int c = 0; c < NC; ++c) f2C += fC[c] * fC[c];
    #pragma unroll
    for (int c = 0; c < NC; ++c) f2D += fD[c] * fD[c];

    const float4* smv = reinterpret_cast<const float4*>(&sm[0][0]);
    #pragma unroll 2
    for (int ii = 0; ii < nact; ++ii) {
        const int loc = act[ii];
        float4 m0 = smv[loc * 4 + 0], m1 = smv[loc * 4 + 1];
        float4 m2v = smv[loc * 4 + 2], m3 = smv[loc * 4 + 3];
        float mm[NC] = {m0.x,m0.y,m0.z,m0.w, m1.x,m1.y,m1.z,m1.w,
                        m2v.x,m2v.y,m2v.z,m2v.w, m3.x,m3.y,m3.z,m3.w};
        float m2 = sm2k[loc];
        float dA = 0.f, dB = 0.f, dC = 0.f, dD = 0.f;
        #pragma unroll
        for (int c = 0; c < NC; ++c) {
            float mc = mm[c];
            dA = fmaf(fA[c], mc, dA);
            dB = fmaf(fB[c], mc, dB);
            dC = fmaf(fC[c], mc, dC);
            dD = fmaf(fD[c], mc, dD);
        }
        float d2A = (f2A - 2.f * dA) + m2;
        float d2B = (f2B - 2.f * dB) + m2;
        float d2C = (f2C - 2.f * dC) + m2;
        float d2D = (f2D - 2.f * dD) + m2;
        bool hA = d2A < BW2, hB = d2B < BW2, hC = d2C < BW2, hD = d2D < BW2;
        if (__any(hA | hB | hC | hD)) {
            if (hA) {
                #pragma unroll
                for (int c = 0; c < NC; ++c) atomicAdd(&snum[loc][c], fA[c]);
                atomicAdd(&sden[loc], 1.f);
            }
            if (hB) {
                #pragma unroll
                for (int c = 0; c < NC; ++c) atomicAdd(&snum[loc][c], fB[c]);
                atomicAdd(&sden[loc], 1.f);
            }
            if (hC) {
                #pragma unroll
                for (int c = 0; c < NC; ++c) atomicAdd(&snum[loc][c], fC[c]);
                atomicAdd(&sden[loc], 1.f);
            }
            if (hD) {
                #pragma unroll
                for (int c = 0; c < NC; ++c) atomicAdd(&snum[loc][c], fD[c]);
                atomicAdd(&sden[loc], 1.f);
            }
        }
    }

    __syncthreads();
    for (int i = tid; i < KPB * NC; i += TPB) {
        float v = (&snum[0][0])[i];
        if (v != 0.f) atomicAdd(&gnumA[kbeg * NC + i], v);
    }
    if (tid < KPB) {
        float v = sden[tid];
        if (v != 0.f) atomicAdd(&gdenA[kbeg + tid], v);
    }
}

// Label: LDS-staged means + 2 points/thread (strided by TPB) + k-unroll 4
// -> 8 independent FMA chains in flight per wave.
__global__ __launch_bounds__(TPB, 4) void ms_label(const float* __restrict__ feat,
                                                   float* __restrict__ ws,
                                                   float* __restrict__ out) {
    __shared__ float sm[NK][NC];
    __shared__ float sm2[NK];
    int* wsi = (int*)ws;
    int total = 0;
    #pragma unroll
    for (int i = 0; i < NB * KS; ++i) total += wsi[ACNT_OFF + i];
    const int finR = wsi[FIN_OFF], finM = wsi[FIN_OFF + 1];

    const int b = blockIdx.x / LNT;
    const int tile = blockIdx.x % LNT;
    const int tid = threadIdx.x;
    float* mPrev = ws + MEANS_OFF + (size_t)finM * NB * NK * NC + (size_t)b * NK * NC;

    if (total == 0) {
        if (tid < NK) {
            const float4* mp4 = reinterpret_cast<const float4*>(mPrev + tid * NC);
            float4* s4 = reinterpret_cast<float4*>(&sm[tid][0]);
            float4 a = mp4[0], q = mp4[1], r = mp4[2], s = mp4[3];
            s4[0] = a; s4[1] = q; s4[2] = r; s4[3] = s;
            sm2[tid] = ws[M2G_OFF + b * NK + tid];
            if (tile == 0) {
                float4* mo4 = reinterpret_cast<float4*>(out + (size_t)NB * NP +
                                                        (size_t)b * NK * NC + tid * NC);
                mo4[0] = a; mo4[1] = q; mo4[2] = r; mo4[3] = s;
            }
        }
    } else {
        float* gnumR = ws + GNUM_OFF + (size_t)finR * NB * NK * NC + (size_t)b * NK * NC;
        float* gdenR = ws + GDEN_OFF + finR * NB * NK + b * NK;
        if (tid < NK) {
            const int k = tid;
            float den = gdenR[k];
            const float4* gn4 = reinterpret_cast<const float4*>(gnumR + k * NC);
            const float4* mp4 = reinterpret_cast<const float4*>(mPrev + k * NC);
            float4 g0 = gn4[0], g1 = gn4[1], g2 = gn4[2], g3 = gn4[3];
            float4 o0 = mp4[0], o1 = mp4[1], o2 = mp4[2], o3 = mp4[3];
            float gg[NC] = {g0.x,g0.y,g0.z,g0.w, g1.x,g1.y,g1.z,g1.w,
                            g2.x,g2.y,g2.z,g2.w, g3.x,g3.y,g3.z,g3.w};
            float oo[NC] = {o0.x,o0.y,o0.z,o0.w, o1.x,o1.y,o1.z,o1.w,
                            o2.x,o2.y,o2.z,o2.w, o3.x,o3.y,o3.z,o3.w};
            float inv = fmaxf(den, 1.f);
            bool pos = den > 0.f;
            float nm[NC];
            #pragma unroll
            for (int c = 0; c < NC; ++c) nm[c] = pos ? (gg[c] / inv) : oo[c];
            #pragma unroll
            for (int c = 0; c < NC; ++c) sm[k][c] = nm[c];
            float s = 0.f;
            #pragma unroll
            for (int c = 0; c < NC; ++c) s += nm[c] * nm[c];
            sm2[k] = s;
            if (tile == 0) {
                float* mo = out + (size_t)NB * NP + (size_t)b * NK * NC + k * NC;
                float4* mo4 = reinterpret_cast<float4*>(mo);
                mo4[0] = make_float4(nm[0], nm[1], nm[2], nm[3]);
                mo4[1] = make_float4(nm[4], nm[5], nm[6], nm[7]);
                mo4[2] = make_float4(nm[8], nm[9], nm[10], nm[11]);
                mo4[3] = make_float4(nm[12], nm[13], nm[14], nm[15]);
            }
        }
    }

    const int pA = tile * LTILEP + tid;
    const int pB = pA + TPB;
    float frA[NC], frB[NC];
    #pragma unroll
    for (int c = 0; c < NC; ++c) {
        const float* row = feat + ((size_t)b * NC + c) * NP;
        frA[c] = row[pA];
        frB[c] = row[pB];
    }
    float f2A = 0.f, f2B = 0.f;
    #pragma unroll
    for (int c = 0; c < NC; ++c) f2A += frA[c] * frA[c];
    #pragma unroll
    for (int c = 0; c < NC; ++c) f2B += frB[c] * frB[c];
    __syncthreads();

    float bestA = 3.4e38f, bestB = 3.4e38f;
    int biA = 0, biB = 0;
    const float4* smv = reinterpret_cast<const float4*>(&sm[0][0]);
    #pragma unroll 4
    for (int k = 0; k < NK; ++k) {
        float4 m0 = smv[k * 4 + 0], m1 = smv[k * 4 + 1];
        float4 m2v = smv[k * 4 + 2], m3 = smv[k * 4 + 3];
        float mm[NC] = {m0.x,m0.y,m0.z,m0.w, m1.x,m1.y,m1.z,m1.w,
                        m2v.x,m2v.y,m2v.z,m2v.w, m3.x,m3.y,m3.z,m3.w};
        float m2 = sm2[k];
        float dA = 0.f, dB = 0.f;
        #pragma unroll
        for (int c = 0; c < NC; ++c) {
            float mc = mm[c];
            dA = fmaf(frA[c], mc, dA);
            dB = fmaf(frB[c], mc, dB);
        }
        float d2A = (f2A - 2.f * dA) + m2;
        float d2B = (f2B - 2.f * dB) + m2;
        if (d2A < bestA) { bestA = d2A; biA = k; }
        if (d2B < bestB) { bestB = d2B; biB = k; }
    }

    out[(size_t)b * NP + pA] = (bestA < BW2) ? (float)(biA + 1) : 0.f;
    out[(size_t)b * NP + pB] = (bestB < BW2) ? (float)(biB + 1) : 0.f;
}

extern "C" void kernel_launch(void* const* d_in, const int* in_sizes, int n_in,
                              void* d_out, int out_size, void* d_ws, size_t ws_size,
                              hipStream_t stream) {
    const float* feat = (const float*)d_in[0];
    const int* seed = (const int*)d_in[1];
    float* out = (float*)d_out;
    float* ws = (float*)d_ws;

    ms_init<<<84, 256, 0, stream>>>(feat, seed, ws);
    for (int i = 0; i < NITER; ++i) {
        ms_accum<<<NB * NTILES * KS, TPB, 0, stream>>>(
            feat, ws, (i + 2) % 3, i % 3, (i + 1) % 3, (i + 1) & 1, i & 1, i);
    }
    ms_label<<<NB * LNT, TPB, 0, stream>>>(feat, ws, out);
}

// Round 17
// 78.872 us; speedup vs baseline: 1.0299x; 1.0299x over previous
//
#include <hip/hip_runtime.h>

#define NB 4
#define NC 16
#define NP 76800
#define NK 100
#define NITER 10
#define BW2 0.0256f
#define TPB 256
#define PT 4
#define TILEP (TPB*PT)        // 1024 points per it>=1 accum block
#define NTILES (NP/TILEP)     // 75
#define KS 4                  // k-split
#define KPB (NK/KS)           // 25
// it0 accum: 6 points/thread
#define PT0 6
#define TILEP0 (TPB*PT0)      // 1536
#define NTILES0 (NP/TILEP0)   // 50
// label: 2 points/thread, strided by TPB (both coalesced)
#define LPT 2
#define LTILEP (TPB*LPT)      // 512
#define LNT (NP/LTILEP)       // 150

// ws float-offsets
#define MEANS_OFF 0                            // [2][NB*NK][NC]
#define M2G_OFF   (MEANS_OFF + 2*NB*NK*NC)     // [NB*NK] m2 of current global means
#define GNUM_OFF  (M2G_OFF + NB*NK)            // [3][NB*NK][NC]
#define GDEN_OFF  (GNUM_OFF + 3*NB*NK*NC)      // [3][NB*NK]
#define ACNT_OFF  (GDEN_OFF + 3*NB*NK)         // int[NB*KS] active counts
#define FIN_OFF   (ACNT_OFF + NB*KS)           // int[2]: finalR, finalM

__global__ void ms_init(const float* __restrict__ feat, const int* __restrict__ seed,
                        float* __restrict__ ws) {
    int t = blockIdx.x * blockDim.x + threadIdx.x;
    int stride = gridDim.x * blockDim.x;
    int* wsi = (int*)ws;
    for (int i = t; i < 3 * NB * NK * NC + 3 * NB * NK; i += stride)
        ws[GNUM_OFF + i] = 0.f;
    if (t < NB * KS) wsi[ACNT_OFF + t] = KPB;
    if (t < 2) wsi[FIN_OFF + t] = 0;
    if (t < NB * NK) {
        int b = t / NK;
        int idx = seed[t];
        float nm[NC];
        #pragma unroll
        for (int c = 0; c < NC; ++c) nm[c] = feat[((size_t)b * NC + c) * NP + idx];
        float s = 0.f;
        #pragma unroll
        for (int c = 0; c < NC; ++c) s += nm[c] * nm[c];
        float* m = ws + MEANS_OFF + NB * NK * NC + t * NC;  // buffer 1 = means_{-1}
        #pragma unroll
        for (int c = 0; c < NC; ++c) m[c] = nm[c];
        ws[M2G_OFF + t] = s;
    }
}

// Iteration 0 only: update is identity (all dens 0); means_{-1} live in means
// buffer 1. LDS-staged means, 6 points/thread to maximize FMA per mean access.
__global__ __launch_bounds__(TPB, 3) void ms_accum0(const float* __restrict__ feat,
                                                    float* __restrict__ ws) {
    __shared__ float sm[KPB][NC];
    __shared__ float sm2k[KPB];
    __shared__ float snum[KPB][NC];
    __shared__ float sden[KPB];
    int* wsi = (int*)ws;

    const int bid = blockIdx.x;
    const int ks = bid & (KS - 1);
    const int t2 = bid >> 2;
    const int b = t2 / NTILES0;
    const int tile = t2 % NTILES0;
    const int tid = threadIdx.x;
    const int kbeg = ks * KPB;

    // it0 buffer roles: read means[1] (means_{-1}); accumulate gnum[0]; zero gnum[1]
    float* gnumA = ws + GNUM_OFF + (size_t)b * NK * NC;                       // idx 0
    float* gdenA = ws + GDEN_OFF + b * NK;
    float* gnumZ = ws + GNUM_OFF + (size_t)1 * NB * NK * NC + (size_t)b * NK * NC;
    float* gdenZ = ws + GDEN_OFF + 1 * NB * NK + b * NK;
    float* mPrev = ws + MEANS_OFF + (size_t)1 * NB * NK * NC + (size_t)b * NK * NC;
    float* mCur  = ws + MEANS_OFF + (size_t)b * NK * NC;                      // buffer 0

    const bool isPersist = (ks == 0 && tile == 0);

    for (int i = tid; i < KPB * NC; i += TPB) (&snum[0][0])[i] = 0.f;
    if (tid < KPB) sden[tid] = 0.f;
    // identity update: persist copies means buffer1 -> buffer0 for it1's prologue
    if (isPersist && tid < NK) {
        const float4* mp4 = reinterpret_cast<const float4*>(mPrev + tid * NC);
        float4* mc4 = reinterpret_cast<float4*>(mCur + tid * NC);
        mc4[0] = mp4[0]; mc4[1] = mp4[1]; mc4[2] = mp4[2]; mc4[3] = mp4[3];
        if (tid == 0) { wsi[FIN_OFF] = 0; wsi[FIN_OFF + 1] = 0; }
    }
    if (ks == 1 && tile == 0) {  // zero it1's accumulation buffer
        for (int i = tid; i < NK * NC; i += TPB) gnumZ[i] = 0.f;
        if (tid < NK) gdenZ[tid] = 0.f;
    }
    // stage this block's KPB means + m2 into LDS
    if (tid < KPB) {
        const int k = kbeg + tid;
        const float4* mp4 = reinterpret_cast<const float4*>(mPrev + k * NC);
        float4* s4 = reinterpret_cast<float4*>(&sm[tid][0]);
        s4[0] = mp4[0]; s4[1] = mp4[1]; s4[2] = mp4[2]; s4[3] = mp4[3];
        sm2k[tid] = ws[M2G_OFF + b * NK + k];
    }
    __syncthreads();

    // ---- load 6 points per thread: 4 via float4 + 2 via float2 (alignment-safe) ----
    const int pBase = tile * TILEP0;
    float f[PT0][NC];
    float fq[PT0];
    #pragma unroll
    for (int c = 0; c < NC; ++c) {
        const float* row = feat + ((size_t)b * NC + c) * NP + pBase;
        float4 v = *reinterpret_cast<const float4*>(row + tid * 4);
        float2 w = *reinterpret_cast<const float2*>(row + 1024 + tid * 2);
        f[0][c] = v.x; f[1][c] = v.y; f[2][c] = v.z; f[3][c] = v.w;
        f[4][c] = w.x; f[5][c] = w.y;
    }
    #pragma unroll
    for (int j = 0; j < PT0; ++j) {
        float s = 0.f;
        #pragma unroll
        for (int c = 0; c < NC; ++c) s += f[j][c] * f[j][c];
        fq[j] = s;
    }

    // ---- hot loop: 25 k, LDS-broadcast means, 6-way ILP FMA chains ----
    const float4* smv = reinterpret_cast<const float4*>(&sm[0][0]);
    #pragma unroll 2
    for (int loc = 0; loc < KPB; ++loc) {
        float4 m0 = smv[loc * 4 + 0], m1 = smv[loc * 4 + 1];
        float4 m2v = smv[loc * 4 + 2], m3 = smv[loc * 4 + 3];
        float mm[NC] = {m0.x,m0.y,m0.z,m0.w, m1.x,m1.y,m1.z,m1.w,
                        m2v.x,m2v.y,m2v.z,m2v.w, m3.x,m3.y,m3.z,m3.w};
        float m2 = sm2k[loc];
        float d[PT0];
        #pragma unroll
        for (int j = 0; j < PT0; ++j) d[j] = 0.f;
        #pragma unroll
        for (int c = 0; c < NC; ++c) {
            float mc = mm[c];
            #pragma unroll
            for (int j = 0; j < PT0; ++j) d[j] = fmaf(f[j][c], mc, d[j]);
        }
        float d2v[PT0];
        bool h[PT0];
        bool anyh = false;
        #pragma unroll
        for (int j = 0; j < PT0; ++j) {
            d2v[j] = (fq[j] - 2.f * d[j]) + m2;
            h[j] = d2v[j] < BW2;
            anyh |= h[j];
        }
        if (__any(anyh)) {  // rare
            #pragma unroll
            for (int j = 0; j < PT0; ++j) if (h[j]) {
                #pragma unroll
                for (int c = 0; c < NC; ++c) atomicAdd(&snum[loc][c], f[j][c]);
                atomicAdd(&sden[loc], 1.f);
            }
        }
    }

    // ---- flush block-local sums (only nonzero entries; usually none) ----
    __syncthreads();
    for (int i = tid; i < KPB * NC; i += TPB) {
        float v = (&snum[0][0])[i];
        if (v != 0.f) atomicAdd(&gnumA[kbeg * NC + i], v);
    }
    if (tid < KPB) {
        float v = sden[tid];
        if (v != 0.f) atomicAdd(&gdenA[kbeg + tid], v);
    }
}

// it >= 1: per-k bitwise convergence skip (exact) + global-convergence early exit.
__global__ __launch_bounds__(TPB, 4) void ms_accum(const float* __restrict__ feat,
                                                   float* __restrict__ ws,
                                                   int rIdx, int aIdx, int zIdx,
                                                   int prevM, int curM, int it) {
    __shared__ float sm[KPB][NC];
    __shared__ float sm2k[KPB];
    __shared__ float snum[KPB][NC];
    __shared__ float sden[KPB];
    __shared__ unsigned char sflag[KPB];
    __shared__ short act[KPB];
    __shared__ int nact;
    int* wsi = (int*)ws;

    {   // global-convergence early exit (uniform scalar reads)
        int total = 0;
        #pragma unroll
        for (int i = 0; i < NB * KS; ++i) total += wsi[ACNT_OFF + i];
        if (total == 0) return;
    }

    const int bid = blockIdx.x;
    const int ks = bid & (KS - 1);
    const int t2 = bid >> 2;
    const int b = t2 / NTILES;
    const int tile = t2 % NTILES;
    const int tid = threadIdx.x;
    const int kbeg = ks * KPB;

    float* gnumR = ws + GNUM_OFF + (size_t)rIdx * NB * NK * NC + (size_t)b * NK * NC;
    float* gnumA = ws + GNUM_OFF + (size_t)aIdx * NB * NK * NC + (size_t)b * NK * NC;
    float* gnumZ = ws + GNUM_OFF + (size_t)zIdx * NB * NK * NC + (size_t)b * NK * NC;
    float* gdenR = ws + GDEN_OFF + rIdx * NB * NK + b * NK;
    float* gdenA = ws + GDEN_OFF + aIdx * NB * NK + b * NK;
    float* gdenZ = ws + GDEN_OFF + zIdx * NB * NK + b * NK;
    float* mPrev = ws + MEANS_OFF + (size_t)prevM * NB * NK * NC + (size_t)b * NK * NC;
    float* mCur  = ws + MEANS_OFF + (size_t)curM  * NB * NK * NC + (size_t)b * NK * NC;

    const bool isPersist = (ks == 0 && tile == 0);

    for (int i = tid; i < KPB * NC; i += TPB) (&snum[0][0])[i] = 0.f;
    if (tid < KPB) sden[tid] = 0.f;

    const int nloc = isPersist ? NK : KPB;
    if (tid < nloc) {
        const int k = isPersist ? tid : (kbeg + tid);
        float den = gdenR[k];
        const float4* gn4 = reinterpret_cast<const float4*>(gnumR + k * NC);
        const float4* mp4 = reinterpret_cast<const float4*>(mPrev + k * NC);
        float4 g0 = gn4[0], g1 = gn4[1], g2 = gn4[2], g3 = gn4[3];
        float4 o0 = mp4[0], o1 = mp4[1], o2 = mp4[2], o3 = mp4[3];
        float gg[NC] = {g0.x,g0.y,g0.z,g0.w, g1.x,g1.y,g1.z,g1.w,
                        g2.x,g2.y,g2.z,g2.w, g3.x,g3.y,g3.z,g3.w};
        float oo[NC] = {o0.x,o0.y,o0.z,o0.w, o1.x,o1.y,o1.z,o1.w,
                        o2.x,o2.y,o2.z,o2.w, o3.x,o3.y,o3.z,o3.w};
        float inv = fmaxf(den, 1.f);
        bool pos = den > 0.f;
        float nm[NC];
        #pragma unroll
        for (int c = 0; c < NC; ++c) nm[c] = pos ? (gg[c] / inv) : oo[c];
        bool same = true;
        #pragma unroll
        for (int c = 0; c < NC; ++c)
            same = same && (__float_as_uint(nm[c]) == __float_as_uint(oo[c]));
        float s = 0.f;
        #pragma unroll
        for (int c = 0; c < NC; ++c) s += nm[c] * nm[c];
        const int loc = k - kbeg;
        if (loc >= 0 && loc < KPB) {
            #pragma unroll
            for (int c = 0; c < NC; ++c) sm[loc][c] = nm[c];
            sm2k[loc] = s;
            sflag[loc] = same ? (unsigned char)1 : (unsigned char)0;
        }
        if (isPersist) {
            float4* mc4 = reinterpret_cast<float4*>(mCur + k * NC);
            mc4[0] = make_float4(nm[0], nm[1], nm[2], nm[3]);
            mc4[1] = make_float4(nm[4], nm[5], nm[6], nm[7]);
            mc4[2] = make_float4(nm[8], nm[9], nm[10], nm[11]);
            mc4[3] = make_float4(nm[12], nm[13], nm[14], nm[15]);
            ws[M2G_OFF + b * NK + k] = s;
            if (same) {  // converged k: sums bitwise equal -> copy
                float4* ga4 = reinterpret_cast<float4*>(gnumA + k * NC);
                ga4[0] = g0; ga4[1] = g1; ga4[2] = g2; ga4[3] = g3;
                gdenA[k] = den;
            }
            if (tid == 0) { wsi[FIN_OFF] = aIdx; wsi[FIN_OFF + 1] = curM; }
        }
    }
    if (ks == 1 && tile == 0) {
        for (int i = tid; i < NK * NC; i += TPB) gnumZ[i] = 0.f;
        if (tid < NK) gdenZ[tid] = 0.f;
    }
    __syncthreads();

    if (tid == 0) {
        int n = 0;
        for (int loc = 0; loc < KPB; ++loc)
            if (!sflag[loc]) act[n++] = (short)loc;
        nact = n;
        if (tile == 0) wsi[ACNT_OFF + b * KS + ks] = n;
    }
    __syncthreads();
    if (nact == 0) return;

    const int p0 = tile * TILEP + tid * PT;
    float fA[NC], fB[NC], fC[NC], fD[NC];
    #pragma unroll
    for (int c = 0; c < NC; ++c) {
        float4 v = *reinterpret_cast<const float4*>(feat + ((size_t)b * NC + c) * NP + p0);
        fA[c] = v.x; fB[c] = v.y; fC[c] = v.z; fD[c] = v.w;
    }
    float f2A = 0.f, f2B = 0.f, f2C = 0.f, f2D = 0.f;
    #pragma unroll
    for (int c = 0; c < NC; ++c) f2A += fA[c] * fA[c];
    #pragma unroll
    for (int c = 0; c < NC; ++c) f2B += fB[c] * fB[c];
    #pragma unroll
    for (int c = 0; c < NC; ++c) f2C += fC[c] * fC[c];
    #pragma unroll
    for (int c = 0; c < NC; ++c) f2D += fD[c] * fD[c];

    const float4* smv = reinterpret_cast<const float4*>(&sm[0][0]);
    #pragma unroll 2
    for (int ii = 0; ii < nact; ++ii) {
        const int loc = act[ii];
        float4 m0 = smv[loc * 4 + 0], m1 = smv[loc * 4 + 1];
        float4 m2v = smv[loc * 4 + 2], m3 = smv[loc * 4 + 3];
        float mm[NC] = {m0.x,m0.y,m0.z,m0.w, m1.x,m1.y,m1.z,m1.w,
                        m2v.x,m2v.y,m2v.z,m2v.w, m3.x,m3.y,m3.z,m3.w};
        float m2 = sm2k[loc];
        float dA = 0.f, dB = 0.f, dC = 0.f, dD = 0.f;
        #pragma unroll
        for (int c = 0; c < NC; ++c) {
            float mc = mm[c];
            dA = fmaf(fA[c], mc, dA);
            dB = fmaf(fB[c], mc, dB);
            dC = fmaf(fC[c], mc, dC);
            dD = fmaf(fD[c], mc, dD);
        }
        float d2A = (f2A - 2.f * dA) + m2;
        float d2B = (f2B - 2.f * dB) + m2;
        float d2C = (f2C - 2.f * dC) + m2;
        float d2D = (f2D - 2.f * dD) + m2;
        bool hA = d2A < BW2, hB = d2B < BW2, hC = d2C < BW2, hD = d2D < BW2;
        if (__any(hA | hB | hC | hD)) {
            if (hA) {
                #pragma unroll
                for (int c = 0; c < NC; ++c) atomicAdd(&snum[loc][c], fA[c]);
                atomicAdd(&sden[loc], 1.f);
            }
            if (hB) {
                #pragma unroll
                for (int c = 0; c < NC; ++c) atomicAdd(&snum[loc][c], fB[c]);
                atomicAdd(&sden[loc], 1.f);
            }
            if (hC) {
                #pragma unroll
                for (int c = 0; c < NC; ++c) atomicAdd(&snum[loc][c], fC[c]);
                atomicAdd(&sden[loc], 1.f);
            }
            if (hD) {
                #pragma unroll
                for (int c = 0; c < NC; ++c) atomicAdd(&snum[loc][c], fD[c]);
                atomicAdd(&sden[loc], 1.f);
            }
        }
    }

    __syncthreads();
    for (int i = tid; i < KPB * NC; i += TPB) {
        float v = (&snum[0][0])[i];
        if (v != 0.f) atomicAdd(&gnumA[kbeg * NC + i], v);
    }
    if (tid < KPB) {
        float v = sden[tid];
        if (v != 0.f) atomicAdd(&gdenA[kbeg + tid], v);
    }
}

// Label: LDS-staged means + 2 points/thread (strided by TPB) + unroll-2 over k
__global__ __launch_bounds__(TPB, 4) void ms_label(const float* __restrict__ feat,
                                                   float* __restrict__ ws,
                                                   float* __restrict__ out) {
    __shared__ float sm[NK][NC];
    __shared__ float sm2[NK];
    int* wsi = (int*)ws;
    int total = 0;
    #pragma unroll
    for (int i = 0; i < NB * KS; ++i) total += wsi[ACNT_OFF + i];
    const int finR = wsi[FIN_OFF], finM = wsi[FIN_OFF + 1];

    const int b = blockIdx.x / LNT;
    const int tile = blockIdx.x % LNT;
    const int tid = threadIdx.x;
    float* mPrev = ws + MEANS_OFF + (size_t)finM * NB * NK * NC + (size_t)b * NK * NC;

    if (total == 0) {
        if (tid < NK) {
            const float4* mp4 = reinterpret_cast<const float4*>(mPrev + tid * NC);
            float4* s4 = reinterpret_cast<float4*>(&sm[tid][0]);
            float4 a = mp4[0], q = mp4[1], r = mp4[2], s = mp4[3];
            s4[0] = a; s4[1] = q; s4[2] = r; s4[3] = s;
            sm2[tid] = ws[M2G_OFF + b * NK + tid];
            if (tile == 0) {
                float4* mo4 = reinterpret_cast<float4*>(out + (size_t)NB * NP +
                                                        (size_t)b * NK * NC + tid * NC);
                mo4[0] = a; mo4[1] = q; mo4[2] = r; mo4[3] = s;
            }
        }
    } else {
        float* gnumR = ws + GNUM_OFF + (size_t)finR * NB * NK * NC + (size_t)b * NK * NC;
        float* gdenR = ws + GDEN_OFF + finR * NB * NK + b * NK;
        if (tid < NK) {
            const int k = tid;
            float den = gdenR[k];
            const float4* gn4 = reinterpret_cast<const float4*>(gnumR + k * NC);
            const float4* mp4 = reinterpret_cast<const float4*>(mPrev + k * NC);
            float4 g0 = gn4[0], g1 = gn4[1], g2 = gn4[2], g3 = gn4[3];
            float4 o0 = mp4[0], o1 = mp4[1], o2 = mp4[2], o3 = mp4[3];
            float gg[NC] = {g0.x,g0.y,g0.z,g0.w, g1.x,g1.y,g1.z,g1.w,
                            g2.x,g2.y,g2.z,g2.w, g3.x,g3.y,g3.z,g3.w};
            float oo[NC] = {o0.x,o0.y,o0.z,o0.w, o1.x,o1.y,o1.z,o1.w,
                            o2.x,o2.y,o2.z,o2.w, o3.x,o3.y,o3.z,o3.w};
            float inv = fmaxf(den, 1.f);
            bool pos = den > 0.f;
            float nm[NC];
            #pragma unroll
            for (int c = 0; c < NC; ++c) nm[c] = pos ? (gg[c] / inv) : oo[c];
            #pragma unroll
            for (int c = 0; c < NC; ++c) sm[k][c] = nm[c];
            float s = 0.f;
            #pragma unroll
            for (int c = 0; c < NC; ++c) s += nm[c] * nm[c];
            sm2[k] = s;
            if (tile == 0) {
                float* mo = out + (size_t)NB * NP + (size_t)b * NK * NC + k * NC;
                float4* mo4 = reinterpret_cast<float4*>(mo);
                mo4[0] = make_float4(nm[0], nm[1], nm[2], nm[3]);
                mo4[1] = make_float4(nm[4], nm[5], nm[6], nm[7]);
                mo4[2] = make_float4(nm[8], nm[9], nm[10], nm[11]);
                mo4[3] = make_float4(nm[12], nm[13], nm[14], nm[15]);
            }
        }
    }

    const int pA = tile * LTILEP + tid;
    const int pB = pA + TPB;
    float frA[NC], frB[NC];
    #pragma unroll
    for (int c = 0; c < NC; ++c) {
        const float* row = feat + ((size_t)b * NC + c) * NP;
        frA[c] = row[pA];
        frB[c] = row[pB];
    }
    float f2A = 0.f, f2B = 0.f;
    #pragma unroll
    for (int c = 0; c < NC; ++c) f2A += frA[c] * frA[c];
    #pragma unroll
    for (int c = 0; c < NC; ++c) f2B += frB[c] * frB[c];
    __syncthreads();

    float bestA = 3.4e38f, bestB = 3.4e38f;
    int biA = 0, biB = 0;
    const float4* smv = reinterpret_cast<const float4*>(&sm[0][0]);
    #pragma unroll 2
    for (int k = 0; k < NK; ++k) {
        float4 m0 = smv[k * 4 + 0], m1 = smv[k * 4 + 1];
        float4 m2v = smv[k * 4 + 2], m3 = smv[k * 4 + 3];
        float mm[NC] = {m0.x,m0.y,m0.z,m0.w, m1.x,m1.y,m1.z,m1.w,
                        m2v.x,m2v.y,m2v.z,m2v.w, m3.x,m3.y,m3.z,m3.w};
        float m2 = sm2[k];
        float dA = 0.f, dB = 0.f;
        #pragma unroll
        for (int c = 0; c < NC; ++c) {
            float mc = mm[c];
            dA = fmaf(frA[c], mc, dA);
            dB = fmaf(frB[c], mc, dB);
        }
        float d2A = (f2A - 2.f * dA) + m2;
        float d2B = (f2B - 2.f * dB) + m2;
        if (d2A < bestA) { bestA = d2A; biA = k; }
        if (d2B < bestB) { bestB = d2B; biB = k; }
    }

    out[(size_t)b * NP + pA] = (bestA < BW2) ? (float)(biA + 1) : 0.f;
    out[(size_t)b * NP + pB] = (bestB < BW2) ? (float)(biB + 1) : 0.f;
}

extern "C" void kernel_launch(void* const* d_in, const int* in_sizes, int n_in,
                              void* d_out, int out_size, void* d_ws, size_t ws_size,
                              hipStream_t stream) {
    const float* feat = (const float*)d_in[0];
    const int* seed = (const int*)d_in[1];
    float* out = (float*)d_out;
    float* ws = (float*)d_ws;

    ms_init<<<84, 256, 0, stream>>>(feat, seed, ws);
    ms_accum0<<<NB * NTILES0 * KS, TPB, 0, stream>>>(feat, ws);
    for (int i = 1; i < NITER; ++i) {
        ms_accum<<<NB * NTILES * KS, TPB, 0, stream>>>(
            feat, ws, (i + 2) % 3, i % 3, (i + 1) % 3, (i + 1) & 1, i & 1, i);
    }
    ms_label<<<NB * LNT, TPB, 0, stream>>>(feat, ws, out);
}